// Round 15
// baseline (15855.812 us; speedup 1.0000x reference)
//
#include <hip/hip_runtime.h>
#include <hip/hip_bf16.h>
#include <math.h>

// R15: CRITICAL FIX — output dtype. The stub contract says d_out follows the
// REFERENCE output dtype = float32 => float*. All rounds since R4 wrote bf16
// into an fp32 buffer => readback scrambled (each read float ~ packs two of
// my bf16s; tail memset-0) => decorrelated comparison => the constant
// 4.2266845703125e-3 regardless of compute changes (R13's thousands of code
// flips didn't move it; only output-bit changes in R9/R10 did).
// Pipeline = R6: fp64 encoder -> fp32 z (best estimate of fp32 gold),
// np-exact fp32 VQ (pairwise-8 s1/cn, fmaf dot, fl(fl(s1-2M)+cn), strict-<),
// straight-through fl(z+fl(q-z)), fp32 decoder, FP32 OUTPUT WRITES.

// ---------------------------------------------------------------------------
// Encoder direct conv, fp64 accumulate. TIn float/double, TOut float/double.
// ---------------------------------------------------------------------------
template<int K, int STRIDE, int PAD, bool IN_RELU, bool OUT_RELU, bool RES_ADD,
         typename TIn, typename TOut>
__global__ __launch_bounds__(256)
void conv_enc64(const TIn* __restrict__ in, const float* __restrict__ w,
                const float* __restrict__ bias, const double* __restrict__ res,
                TOut* __restrict__ out,
                int B, int Cin, int Hin, int Win, int Cout, int Hout, int Wout)
{
    constexpr int PIX = 4, COT = 4;
    constexpr int WIN = STRIDE * (PIX - 1) + K;
    int wg = Wout >> 2;
    long idx = (long)blockIdx.x * 256 + threadIdx.x;
    long total = (long)B * (Cout >> 2) * Hout * wg;
    if (idx >= total) return;
    int owg = (int)(idx % wg);  long t = idx / wg;
    int oh  = (int)(t % Hout);  t /= Hout;
    int cog = (int)(t % (Cout >> 2));
    int b   = (int)(t / (Cout >> 2));
    int ow0 = owg << 2, co0 = cog << 2;

    double acc[COT][PIX];
    #pragma unroll
    for (int c = 0; c < COT; c++) {
        double bv = (double)bias[co0 + c];
        #pragma unroll
        for (int j = 0; j < PIX; j++) acc[c][j] = bv;
    }

    const int ih0 = oh * STRIDE - PAD;
    const int iwb = ow0 * STRIDE - PAD;
    const long inCH = (long)Hin * Win;
    const int  wCK  = Cin * K * K;

    for (int ci = 0; ci < Cin; ci++) {
        const TIn* inp = in + ((long)b * Cin + ci) * inCH;
        const float* wp = w + ((long)co0 * Cin + ci) * (K * K);
        #pragma unroll
        for (int kh = 0; kh < K; kh++) {
            int ih = ih0 + kh;
            if ((unsigned)ih >= (unsigned)Hin) continue;
            const TIn* rowp = inp + (long)ih * Win;
            double iv[WIN];
            #pragma unroll
            for (int x = 0; x < WIN; x++) {
                int iw = iwb + x;
                double v = ((unsigned)iw < (unsigned)Win) ? (double)rowp[iw] : 0.0;
                iv[x] = IN_RELU ? fmax(v, 0.0) : v;
            }
            #pragma unroll
            for (int c = 0; c < COT; c++) {
                #pragma unroll
                for (int kw = 0; kw < K; kw++) {
                    double wv = (double)wp[c * wCK + kh * K + kw];
                    #pragma unroll
                    for (int j = 0; j < PIX; j++)
                        acc[c][j] = fma(iv[j * STRIDE + kw], wv, acc[c][j]);
                }
            }
        }
    }

    long ostride = (long)Hout * Wout;
    long obase = (((long)b * Cout + co0) * Hout + oh) * Wout + ow0;
    #pragma unroll
    for (int c = 0; c < COT; c++) {
        #pragma unroll
        for (int j = 0; j < PIX; j++) {
            double v = acc[c][j];
            if (RES_ADD) v += res[obase + c * ostride + j];
            if (OUT_RELU) v = fmax(v, 0.0);
            out[obase + c * ostride + j] = (TOut)v;
        }
    }
}

// ---------------------------------------------------------------------------
// Decoder direct conv, fp32.
// ---------------------------------------------------------------------------
template<int K, int STRIDE, int PAD, bool IN_RELU, bool OUT_RELU, bool RES_ADD>
__global__ __launch_bounds__(256)
void conv_direct(const float* __restrict__ in, const float* __restrict__ w,
                 const float* __restrict__ bias, const float* __restrict__ res,
                 float* __restrict__ out,
                 int B, int Cin, int Hin, int Win, int Cout, int Hout, int Wout)
{
    constexpr int PIX = 4;
    constexpr int WIN = STRIDE * (PIX - 1) + K;
    int wg = Wout >> 2;
    long idx = (long)blockIdx.x * 256 + threadIdx.x;
    long total = (long)B * (Cout >> 2) * Hout * wg;
    if (idx >= total) return;
    int owg = (int)(idx % wg);  long t = idx / wg;
    int oh  = (int)(t % Hout);  t /= Hout;
    int cog = (int)(t % (Cout >> 2));
    int b   = (int)(t / (Cout >> 2));
    int ow0 = owg << 2, co0 = cog << 2;

    float acc[4][PIX];
    #pragma unroll
    for (int c = 0; c < 4; c++) {
        float bv = bias[co0 + c];
        #pragma unroll
        for (int j = 0; j < PIX; j++) acc[c][j] = bv;
    }

    const int ih0 = oh * STRIDE - PAD;
    const int iwb = ow0 * STRIDE - PAD;
    const long inCH = (long)Hin * Win;
    const int  wCK  = Cin * K * K;

    for (int ci = 0; ci < Cin; ci++) {
        const float* inp = in + ((long)b * Cin + ci) * inCH;
        const float* wp  = w + ((long)co0 * Cin + ci) * (K * K);
        #pragma unroll
        for (int kh = 0; kh < K; kh++) {
            int ih = ih0 + kh;
            if ((unsigned)ih >= (unsigned)Hin) continue;
            const float* rowp = inp + (long)ih * Win;
            float iv[WIN];
            #pragma unroll
            for (int x = 0; x < WIN; x++) {
                int iw = iwb + x;
                float v = ((unsigned)iw < (unsigned)Win) ? rowp[iw] : 0.f;
                iv[x] = IN_RELU ? fmaxf(v, 0.f) : v;
            }
            #pragma unroll
            for (int c = 0; c < 4; c++) {
                #pragma unroll
                for (int kw = 0; kw < K; kw++) {
                    float wv = wp[c * wCK + kh * K + kw];
                    #pragma unroll
                    for (int j = 0; j < PIX; j++)
                        acc[c][j] = fmaf(iv[j * STRIDE + kw], wv, acc[c][j]);
                }
            }
        }
    }

    long ostride = (long)Hout * Wout;
    long obase = (((long)b * Cout + co0) * Hout + oh) * Wout + ow0;
    #pragma unroll
    for (int c = 0; c < 4; c++) {
        #pragma unroll
        for (int j = 0; j < PIX; j++) {
            float v = acc[c][j];
            if (RES_ADD) v += res[obase + c * ostride + j];
            if (OUT_RELU) v = fmaxf(v, 0.f);
            out[obase + c * ostride + j] = v;
        }
    }
}

// ---------------------------------------------------------------------------
// ConvTranspose2d k=4 s=2 p=1, fp32. Weight (Cin, Cout, 4, 4). FP32 stores.
// ---------------------------------------------------------------------------
template<int COT, bool IN_RELU, bool OUT_RELU, bool OUT_TANH>
__global__ __launch_bounds__(256)
void deconv4x4s2(const float* __restrict__ in, const float* __restrict__ w,
                 const float* __restrict__ bias, float* __restrict__ out,
                 int B, int Cin, int Hin, int Win, int Cout)
{
    int Hout = Hin << 1, Wout = Win << 1;
    int wg = Wout >> 2;
    int ncog = Cout / COT;
    long idx = (long)blockIdx.x * 256 + threadIdx.x;
    long total = (long)B * ncog * Hout * wg;
    if (idx >= total) return;
    int owg = (int)(idx % wg);  long t = idx / wg;
    int oh  = (int)(t % Hout);  t /= Hout;
    int cog = (int)(t % ncog);
    int b   = (int)(t / ncog);
    int ow0 = owg << 2, co0 = cog * COT;

    float acc[COT][4];
    #pragma unroll
    for (int c = 0; c < COT; c++) {
        float bv = bias[co0 + c];
        #pragma unroll
        for (int j = 0; j < 4; j++) acc[c][j] = bv;
    }

    int ah  = (oh + 1) & 1;
    int iwb = ow0 >> 1;
    for (int ci = 0; ci < Cin; ci++) {
        const float* inp = in + ((long)b * Cin + ci) * ((long)Hin * Win);
        const float* wp  = w + ((long)ci * Cout + co0) * 16;
        #pragma unroll
        for (int th = 0; th < 2; th++) {
            int kh = ah + (th << 1);
            int ih = (oh + 1 - kh) >> 1;
            if ((unsigned)ih >= (unsigned)Hin) continue;
            const float* row = inp + (long)ih * Win;
            float i0 = (iwb - 1 >= 0) ? row[iwb - 1] : 0.f;
            float i1 = row[iwb];
            float i2 = row[iwb + 1];
            float i3 = (iwb + 2 < Win) ? row[iwb + 2] : 0.f;
            if (IN_RELU) {
                i0 = fmaxf(i0, 0.f); i1 = fmaxf(i1, 0.f);
                i2 = fmaxf(i2, 0.f); i3 = fmaxf(i3, 0.f);
            }
            #pragma unroll
            for (int c = 0; c < COT; c++) {
                const float* wk = wp + c * 16 + kh * 4;
                float w0 = wk[0], w1 = wk[1], w2 = wk[2], w3 = wk[3];
                acc[c][0] = fmaf(i1, w1, fmaf(i0, w3, acc[c][0]));
                acc[c][1] = fmaf(i2, w0, fmaf(i1, w2, acc[c][1]));
                acc[c][2] = fmaf(i2, w1, fmaf(i1, w3, acc[c][2]));
                acc[c][3] = fmaf(i3, w0, fmaf(i2, w2, acc[c][3]));
            }
        }
    }

    long ostride = (long)Hout * Wout;
    long obase = (((long)b * Cout + co0) * (long)Hout + oh) * Wout + ow0;
    #pragma unroll
    for (int c = 0; c < COT; c++) {
        #pragma unroll
        for (int j = 0; j < 4; j++) {
            float v = acc[c][j];
            if (OUT_RELU) v = fmaxf(v, 0.f);
            if (OUT_TANH) v = tanhf(v);
            out[obase + c * ostride + j] = v;   // fp32 store
        }
    }
}

// numpy pairwise sum-of-squares over 64 fp32 values.
__device__ __forceinline__ float np_sumsq64(const float* v) {
    float r[8];
    #pragma unroll
    for (int j = 0; j < 8; j++) r[j] = __fmul_rn(v[j], v[j]);
    #pragma unroll
    for (int i = 8; i < 64; i += 8) {
        #pragma unroll
        for (int j = 0; j < 8; j++)
            r[j] = __fadd_rn(r[j], __fmul_rn(v[i + j], v[i + j]));
    }
    float s01 = __fadd_rn(r[0], r[1]), s23 = __fadd_rn(r[2], r[3]);
    float s45 = __fadd_rn(r[4], r[5]), s67 = __fadd_rn(r[6], r[7]);
    return __fadd_rn(__fadd_rn(s01, s23), __fadd_rn(s45, s67));
}

__global__ void codenorm_kernel(const float* __restrict__ cb, float* __restrict__ cn)
{
    int k = blockIdx.x * 64 + threadIdx.x;
    if (k >= 512) return;
    float row[64];
    #pragma unroll
    for (int d = 0; d < 64; d++) row[d] = cb[k * 64 + d];
    cn[k] = np_sumsq64(row);
}

// VQ: np-exact fp32 chain; st = fl(z + fl(q-z)).
__global__ __launch_bounds__(256)
void vq_kernel(const float* __restrict__ z, const float* __restrict__ cb,
               const float* __restrict__ cn, float* __restrict__ st,
               double* __restrict__ loss_sum, int B)
{
    long idx = (long)blockIdx.x * 256 + threadIdx.x;
    if (idx >= (long)B * 4096) return;
    int p = (int)(idx & 4095);
    int b = (int)(idx >> 12);
    const float* zp = z + (long)b * 64 * 4096 + p;
    float zr[64];
    #pragma unroll
    for (int d = 0; d < 64; d++) zr[d] = zp[(long)d * 4096];

    float s1 = np_sumsq64(zr);

    float best = INFINITY;
    int bi = 0;
    for (int k = 0; k < 512; k++) {
        const float* ck = cb + k * 64;
        float m = 0.f;
        #pragma unroll
        for (int d = 0; d < 64; d++) m = fmaf(zr[d], ck[d], m);
        float dist = __fadd_rn(__fsub_rn(s1, __fmul_rn(2.f, m)), cn[k]);
        if (dist < best) { best = dist; bi = k; }
    }

    const float* cbest = cb + bi * 64;
    float* sp = st + (long)b * 64 * 4096 + p;
    double ls = 0.0;
    #pragma unroll
    for (int d = 0; d < 64; d++) {
        float qv = cbest[d];
        float diff = __fsub_rn(qv, zr[d]);
        double dd = (double)qv - (double)zr[d];
        ls += dd * dd;
        sp[(long)d * 4096] = __fadd_rn(zr[d], diff);
    }
    #pragma unroll
    for (int off = 32; off > 0; off >>= 1) ls += __shfl_down(ls, off, 64);
    if ((threadIdx.x & 63) == 0) atomicAdd(loss_sum, ls);
}

__global__ void loss_final_kernel(const double* __restrict__ s, float* __restrict__ out)
{
    out[0] = (float)(1.25 * s[0] / 8388608.0);   // fp32 loss store
}

static inline int nblk(long total) { return (int)((total + 255) / 256); }

extern "C" void kernel_launch(void* const* d_in, const int* in_sizes, int n_in,
                              void* d_out, int out_size, void* d_ws, size_t ws_size,
                              hipStream_t stream)
{
    const float* x        = (const float*)d_in[0];
    const float* enc_w1   = (const float*)d_in[1];
    const float* enc_b1   = (const float*)d_in[2];
    const float* enc_w2   = (const float*)d_in[3];
    const float* enc_b2   = (const float*)d_in[4];
    const float* enc_w3   = (const float*)d_in[5];
    const float* enc_b3   = (const float*)d_in[6];
    const float* enc_rw1  = (const float*)d_in[7];
    const float* enc_rb1  = (const float*)d_in[8];
    const float* enc_rw2  = (const float*)d_in[9];
    const float* enc_rb2  = (const float*)d_in[10];
    const float* pvq_w    = (const float*)d_in[11];
    const float* pvq_b    = (const float*)d_in[12];
    const float* codebook = (const float*)d_in[13];
    const float* dec_w1   = (const float*)d_in[14];
    const float* dec_b1   = (const float*)d_in[15];
    const float* dec_rw1  = (const float*)d_in[16];
    const float* dec_rb1  = (const float*)d_in[17];
    const float* dec_rw2  = (const float*)d_in[18];
    const float* dec_rb2  = (const float*)d_in[19];
    const float* dt1_w    = (const float*)d_in[20];
    const float* dt1_b    = (const float*)d_in[21];
    const float* dt2_w    = (const float*)d_in[22];
    const float* dt2_b    = (const float*)d_in[23];

    float* out = (float*)d_out;            // fp32 output buffer (ref dtype)
    char* wsb = (char*)d_ws;

    float*  CN = (float*)wsb;              // 512 floats
    double* LS = (double*)(wsb + 4096);    // 1 double
    const size_t SMALLB = 4352;

    const long eA = 1048576, eB = 524288, eC = 524288, eT = 131072;
    const long eZ = 262144, eQ = 262144;
    const size_t perSampleB = (size_t)(eA + eB + eC + eT) * 8 + (size_t)(eZ + eQ) * 4;

    int Bc = 32;
    while (Bc > 1 && SMALLB + perSampleB * Bc + 1024 > ws_size) Bc >>= 1;
    const int nChunks = 32 / Bc;

    double* A64 = (double*)(wsb + SMALLB);
    double* B64 = A64 + eA * Bc;
    double* C64 = B64 + eB * Bc;
    double* T64 = C64 + eC * Bc;
    float*  Z32 = (float*)(T64 + eT * Bc);
    float*  Qf  = Z32 + eZ * Bc;
    float* Df = (float*)B64;   // decoder fp32 aliases (encoder buffers dead)
    float* Tf = (float*)T64;
    float* Ef = (float*)A64;

    hipMemsetAsync(LS, 0, sizeof(double), stream);
    codenorm_kernel<<<8, 64, 0, stream>>>(codebook, CN);

    for (int c = 0; c < nChunks; c++) {
        const float* xc = x + (long)c * Bc * 3 * 65536;
        float* outc = out + (long)c * Bc * 3 * 65536;

        // ---- encoder (fp64 accumulate -> fp32 z) ----
        conv_enc64<4,2,1,false,true,false><<<nblk((long)Bc*16*128*32), 256, 0, stream>>>(
            xc, enc_w1, enc_b1, nullptr, A64, Bc, 3, 256, 256, 64, 128, 128);
        conv_enc64<4,2,1,false,true,false><<<nblk((long)Bc*32*64*16), 256, 0, stream>>>(
            A64, enc_w2, enc_b2, nullptr, B64, Bc, 64, 128, 128, 128, 64, 64);
        conv_enc64<3,1,1,false,false,false><<<nblk((long)Bc*32*64*16), 256, 0, stream>>>(
            B64, enc_w3, enc_b3, nullptr, C64, Bc, 128, 64, 64, 128, 64, 64);
        for (int i = 0; i < 2; i++) {
            conv_enc64<3,1,1,true,false,false><<<nblk((long)Bc*8*64*16), 256, 0, stream>>>(
                C64, enc_rw1 + (long)i*32*128*9, enc_rb1 + i*32, nullptr, T64,
                Bc, 128, 64, 64, 32, 64, 64);
            conv_enc64<1,1,0,true,false,true><<<nblk((long)Bc*32*64*16), 256, 0, stream>>>(
                T64, enc_rw2 + (long)i*128*32, enc_rb2 + i*128, C64, C64,
                Bc, 32, 64, 64, 128, 64, 64);
        }
        conv_enc64<1,1,0,true,false,false><<<nblk((long)Bc*16*64*16), 256, 0, stream>>>(
            C64, pvq_w, pvq_b, nullptr, Z32, Bc, 128, 64, 64, 64, 64, 64);

        // ---- VQ (np-exact fp32) ----
        vq_kernel<<<Bc * 16, 256, 0, stream>>>(Z32, codebook, CN, Qf, LS, Bc);

        // ---- decoder (fp32), fp32 output stores ----
        conv_direct<3,1,1,false,false,false><<<nblk((long)Bc*32*64*16), 256, 0, stream>>>(
            Qf, dec_w1, dec_b1, nullptr, Df, Bc, 64, 64, 64, 128, 64, 64);
        for (int i = 0; i < 2; i++) {
            conv_direct<3,1,1,true,false,false><<<nblk((long)Bc*8*64*16), 256, 0, stream>>>(
                Df, dec_rw1 + (long)i*32*128*9, dec_rb1 + i*32, nullptr, Tf,
                Bc, 128, 64, 64, 32, 64, 64);
            conv_direct<1,1,0,true,false,true><<<nblk((long)Bc*32*64*16), 256, 0, stream>>>(
                Tf, dec_rw2 + (long)i*128*32, dec_rb2 + i*128, Df, Df,
                Bc, 32, 64, 64, 128, 64, 64);
        }
        deconv4x4s2<4,true,true,false><<<nblk((long)Bc*16*128*32), 256, 0, stream>>>(
            Df, dt1_w, dt1_b, Ef, Bc, 128, 64, 64, 64);
        deconv4x4s2<3,false,false,true><<<nblk((long)Bc*1*256*64), 256, 0, stream>>>(
            Ef, dt2_w, dt2_b, outc, Bc, 64, 128, 128, 3);
    }

    loss_final_kernel<<<1, 1, 0, stream>>>(LS, out + 6291456);
}